// Round 23
// baseline (133.002 us; speedup 1.0000x reference)
//
#include <hip/hip_runtime.h>
#include <hip/hip_bf16.h>

#define HP    66
#define QTOT  (HP*HP)          // 4356
#define NWIN  29
#define NW    (NWIN*NWIN)      // 841
#define KK    7
#define WOFF2 14
#define NZ    15               // dy-chunks for contraction (2 rows each)
#define QB    8                // queries per k_weights block
#define QBN   545              // ceil(QTOT/8)
#define NIT   27               // ceil(841/32)
#define NSEG6 396              // 66 lines x 6 segments of 11
#define PSTR  4368             // wf plane stride in u16 (546 uint4)

// ws float layout:
// 0        : yex    [QTOT][8] interleaved f32
// 8*QTOT   : xex    [QTOT][8] interleaved f32
// 16*QTOT  : x66b   [QTOT] uint4 (8 bf16 channels packed)
// 24*QTOT  : sqye/sqxe/lt66/n2q/n2db/ltb  (6 x QTOT)
// 30*QTOT  : dist   NW*QTOT f32 [w][q]   (reused as accb2 after k_weights)
// + NW*QTOT: wf bf16 [k][w][PSTR]

__global__ __launch_bounds__(256) void k_prep1(const float* __restrict__ x,
    const float* __restrict__ xe, const float* __restrict__ ye,
    const float* __restrict__ lt, float* __restrict__ ws) {
  int p = blockIdx.x * 256 + threadIdx.x;
  if (p >= QTOT) return;
  int i = p / HP, j = p % HP;
  bool in = (i >= 1 && i < HP-1 && j >= 1 && j < HP-1);
  int src = (i-1)*64 + (j-1);
  float vy[8], vx[8], vv[8];
  float sy = 0.f, sx = 0.f;
#pragma unroll
  for (int e = 0; e < 8; ++e) {
    vy[e] = in ? ye[e*4096 + src] : 0.f;
    vx[e] = in ? xe[e*4096 + src] : 0.f;
    vv[e] = in ? x [e*4096 + src] : 0.f;
    sy += vy[e]*vy[e]; sx += vx[e]*vx[e];
  }
  float4* yp = (float4*)(ws + (size_t)p*8);
  float4* xp = (float4*)(ws + 8*QTOT + (size_t)p*8);
  yp[0] = make_float4(vy[0], vy[1], vy[2], vy[3]);
  yp[1] = make_float4(vy[4], vy[5], vy[6], vy[7]);
  xp[0] = make_float4(vx[0], vx[1], vx[2], vx[3]);
  xp[1] = make_float4(vx[4], vx[5], vx[6], vx[7]);
  unsigned wd[4];
#pragma unroll
  for (int e2 = 0; e2 < 4; ++e2) {
    unsigned lo = __bfloat16_as_ushort(__float2bfloat16(vv[2*e2]));
    unsigned hi = __bfloat16_as_ushort(__float2bfloat16(vv[2*e2+1]));
    wd[e2] = lo | (hi << 16);
  }
  uint4* xb = (uint4*)(ws + 16*QTOT);
  uint4 v4; v4.x = wd[0]; v4.y = wd[1]; v4.z = wd[2]; v4.w = wd[3];
  xb[p] = v4;
  ws[24*QTOT + p] = sy;
  ws[25*QTOT + p] = sx;
  ws[26*QTOT + p] = in ? lt[src] : 0.f;
}

__global__ __launch_bounds__(256) void k_prep2(float* __restrict__ ws) {
  int p = blockIdx.x * 256 + threadIdx.x;
  if (p >= QTOT) return;
  int i = p / HP, j = p % HP;
  const float* sqye = ws + 24*QTOT;
  const float* sqxe = ws + 25*QTOT;
  const float* lt66 = ws + 26*QTOT;
  float a = 0.f, b = 0.f, c = 0.f;
  for (int u = -5; u <= 4; ++u) {
    int ii = i + u; if (ii < 0 || ii >= HP) continue;
    for (int v = -5; v <= 4; ++v) {
      int jj = j + v; if (jj < 0 || jj >= HP) continue;
      int o = ii*HP + jj;
      a += sqye[o]; b += sqxe[o]; c += lt66[o];
    }
  }
  ws[27*QTOT + p] = a;
  ws[28*QTOT + p] = b;
  ws[29*QTOT + p] = c * 0.01f;
}

// one block per shift w: dist plane [w][q]; flat LDS; register-rotation box
// [-5,+4] with 6-way segmented lines (chains of 11); coalesced f4 store
__global__ __launch_bounds__(256) void k_dist(const float* __restrict__ ws,
                                              float* __restrict__ dist) {
  __shared__ float4 s4[QTOT/4];         // flat f32[QTOT], 16B aligned
  __shared__ float h[QTOT];
  float* s = (float*)s4;
  int w = blockIdx.x, tid = threadIdx.x;
  int dy = w / NWIN - WOFF2, dx = w % NWIN - WOFF2;
  const float* yex = ws;
  const float* xex = ws + 8*QTOT;
  const float* n2q  = ws + 27*QTOT;
  const float* n2db = ws + 28*QTOT;
  for (int p = tid; p < QTOT; p += 256) {
    int i = p / HP, j = p % HP;
    int ii = i + dy, jj = j + dx;
    float sv = 0.f;
    if (ii >= 0 && ii < HP && jj >= 0 && jj < HP) {
      int p2 = ii*HP + jj;
      const float4* yp = (const float4*)(yex + (size_t)p*8);
      const float4* xp = (const float4*)(xex + (size_t)p2*8);
      float4 a0 = yp[0], a1 = yp[1], b0 = xp[0], b1 = xp[1];
      sv += a0.x*b0.x; sv += a0.y*b0.y; sv += a0.z*b0.z; sv += a0.w*b0.w;
      sv += a1.x*b1.x; sv += a1.y*b1.y; sv += a1.z*b1.z; sv += a1.w*b1.w;
    }
    s[p] = sv;
  }
  __syncthreads();
  for (int task = tid; task < NSEG6; task += 256) {  // h-pass [-5,+4]
    int row = task % HP, seg = task / HP, c0 = seg*11;
    const float* ar = s + row*HP;
    float* hr = h + row*HP;
    float w9[9]; float sum = 0.f;
#pragma unroll
    for (int t = 0; t < 9; ++t) {
      int jj = c0 - 5 + t;
      float v = (jj >= 0) ? ar[jj] : 0.f;
      w9[t] = v; sum += v;
    }
#pragma unroll
    for (int t = 0; t < 11; ++t) {
      int j = c0 + t, jn = j + 4;
      float nv = (jn < HP) ? ar[jn] : 0.f;
      sum += nv;
      hr[j] = sum;
      sum -= w9[t % 9];
      w9[t % 9] = nv;
    }
  }
  __syncthreads();
  for (int task = tid; task < NSEG6; task += 256) {  // v-pass + epilogue -> s
    int col = task % HP, seg = task / HP, r0 = seg*11;
    float w9[9]; float sum = 0.f;
#pragma unroll
    for (int t = 0; t < 9; ++t) {
      int ii = r0 - 5 + t;
      float v = (ii >= 0) ? h[ii*HP + col] : 0.f;
      w9[t] = v; sum += v;
    }
#pragma unroll
    for (int t = 0; t < 11; ++t) {
      int i = r0 + t, in2 = i + 4;
      float nv = (in2 < HP) ? h[in2*HP + col] : 0.f;
      sum += nv;
      float cr = sum;
      int p = i*HP + col;
      int ii = i + dy, jj = col + dx;
      bool valid = (ii >= 0 && ii < HP && jj >= 0 && jj < HP);
      float dv = 1e10f;
      if (valid && !(dy == 0 && dx == 0))
        dv = n2q[p] + n2db[ii*HP + jj] - 2.f * cr;
      s[p] = dv;                        // s dead after h-pass; no race
      sum -= w9[t % 9];
      w9[t % 9] = nv;
    }
  }
  __syncthreads();
  float4* dq = (float4*)(dist + (size_t)w*QTOT);
  for (int p4 = tid; p4 < QTOT/4; p4 += 256)   // coalesced store
    dq[p4] = s4[p4];
}

// 8 queries/block (qb XCD-swizzled); lv[] only; writes into wf[k][w][PSTR]
__global__ __launch_bounds__(256) void k_weights(const float* __restrict__ ws,
    const float* __restrict__ dist, __hip_bfloat16* __restrict__ wf) {
  __shared__ float mh[32], sh[32];
  int tid = threadIdx.x;
  int bid = blockIdx.x;                 // 545 blocks; m204 bijection (68,r=1)
  int xcd = bid & 7, idx = bid >> 3;
  int qb = (xcd == 0) ? idx : (69 + (xcd-1)*68 + idx);
  int qq = tid & (QB-1);
  int q = qb * QB + qq;
  bool qok = q < QTOT;
  int qs = qok ? q : (QTOT - 1);
  int wg = tid >> 3;             // 0..31
  int wave = tid >> 6;           // 0..3
  float invT = __expf(-ws[29*QTOT + qs]);
  float lv[NIT];
#pragma unroll
  for (int it = 0; it < NIT; ++it) {
    int w = wg + it*32;
    lv[it] = (qok && w < NW) ? (-dist[w*QTOT + qs] * invT) : -3.0e38f;
  }
  for (int k = 0; k < KK; ++k) {
    float pm = -3.0e38f;
#pragma unroll
    for (int it = 0; it < NIT; ++it) pm = fmaxf(pm, lv[it]);
    pm = fmaxf(pm, __shfl_xor(pm, 8, 64));
    pm = fmaxf(pm, __shfl_xor(pm, 16, 64));
    pm = fmaxf(pm, __shfl_xor(pm, 32, 64));
    if ((tid & 63) < QB) mh[wave*QB + qq] = pm;
    __syncthreads();
    float m = fmaxf(fmaxf(mh[qq], mh[QB+qq]), fmaxf(mh[2*QB+qq], mh[3*QB+qq]));
    float psum = 0.f;
#pragma unroll
    for (int it = 0; it < NIT; ++it) psum += __expf(lv[it] - m);
    psum += __shfl_xor(psum, 8, 64);
    psum += __shfl_xor(psum, 16, 64);
    psum += __shfl_xor(psum, 32, 64);
    if ((tid & 63) < QB) sh[wave*QB + qq] = psum;
    __syncthreads();
    float invden = 1.0f / (sh[qq] + sh[QB+qq] + sh[2*QB+qq] + sh[3*QB+qq]);
    size_t kbase = (size_t)k*NW*PSTR + q;
#pragma unroll
    for (int it = 0; it < NIT; ++it) {
      int w = wg + it*32;
      if (qok && w < NW) {
        float wgt = __expf(lv[it] - m) * invden;
        wf[kbase + (size_t)w*PSTR] = __float2bfloat16(wgt);
        if (k < KK-1 && wgt > 1e-9f)
          lv[it] += __logf(fmaxf(1.f - wgt, 1e-6f));
      }
    }
    __syncthreads();
  }
}

// one 256t block per (k,w) plane (R21 proven best): FULLY COALESCED in-place
// plane load/store (546 contiguous uint4); box in flat bf16 LDS (17.5KB ->
// 8 blocks/CU); both passes 6-way segmented (chains of 11); a->h, h->a.
__global__ __launch_bounds__(256) void k_boxw(__hip_bfloat16* __restrict__ wfp) {
  __shared__ uint4 au4[546];            // flat bf16[4368]
  __shared__ uint4 hu4[546];            // flat bf16[4368] intermediate
  int bid = blockIdx.x;                 // 0..KK*NW-1
  uint4* plane = (uint4*)(wfp + (size_t)bid*PSTR);
  int tid = threadIdx.x;
  for (int qb = tid; qb < 546; qb += 256)
    au4[qb] = plane[qb];
  __syncthreads();
  const unsigned short* a16 = (const unsigned short*)au4;
  unsigned short* h16 = (unsigned short*)hu4;
  for (int task = tid; task < NSEG6; task += 256) {  // h-pass [-4,+5]
    int row = task % HP, seg = task / HP, c0 = seg*11;
    const unsigned short* ar = a16 + row*HP;
    unsigned short* hr = h16 + row*HP;
    float w9[9]; float sum = 0.f;
#pragma unroll
    for (int t = 0; t < 9; ++t) {
      int jj = c0 - 4 + t;
      float v = (jj >= 0) ? __uint_as_float((unsigned)ar[jj] << 16) : 0.f;
      w9[t] = v; sum += v;
    }
#pragma unroll
    for (int t = 0; t < 11; ++t) {
      int j = c0 + t, jn = j + 5;
      float nv = (jn < HP) ? __uint_as_float((unsigned)ar[jn] << 16) : 0.f;
      sum += nv;
      hr[j] = __bfloat16_as_ushort(__float2bfloat16(sum));
      sum -= w9[t % 9];
      w9[t % 9] = nv;
    }
  }
  __syncthreads();
  unsigned short* a16w = (unsigned short*)au4;
  for (int task = tid; task < NSEG6; task += 256) {  // v-pass [-4,+5]
    int col = task % HP, seg = task / HP, r0 = seg*11;
    float w9[9]; float sum = 0.f;
#pragma unroll
    for (int t = 0; t < 9; ++t) {
      int ii = r0 - 4 + t;
      float v = (ii >= 0) ? __uint_as_float((unsigned)h16[ii*HP + col] << 16) : 0.f;
      w9[t] = v; sum += v;
    }
#pragma unroll
    for (int t = 0; t < 11; ++t) {
      int i = r0 + t, in2 = i + 5;
      float nv = (in2 < HP) ? __uint_as_float((unsigned)h16[in2*HP + col] << 16) : 0.f;
      sum += nv;
      a16w[i*HP + col] = __bfloat16_as_ushort(__float2bfloat16(sum));
      sum -= w9[t % 9];
      w9[t % 9] = nv;
    }
  }
  __syncthreads();
  for (int qb = tid; qb < 546; qb += 256)     // coalesced in-place store
    plane[qb] = au4[qb];
}

// grid (16 tiles of 8x32, NZ=15, KK) = 1680 blocks; full-line wf reads +
// f32 inner loop. BOTH dd-rows' wv loads hoisted up front (2x MLP; second
// row's latency hides under first row's FMA chain).
__global__ __launch_bounds__(256) void k_contract(const float* __restrict__ ws,
    const unsigned short* __restrict__ wfb, float* __restrict__ accb2) {
  __shared__ float4 xtA[9][60];
  __shared__ float4 xtB[9][60];
  int t = blockIdx.x, z = blockIdx.y, k = blockIdx.z, tid = threadIdx.x;
  int I0 = (t >> 1) * 8, J0 = (t & 1) * 32;
  int dylo = -WOFF2 + 2*z;
  int gy0 = I0 + 1 + dylo, gx0 = J0 - 13;
  const uint4* xb = (const uint4*)(ws + 16*QTOT);
  for (int idx = tid; idx < 9*60; idx += 256) {
    int r = idx / 60, cc = idx % 60;
    int gy = gy0 + r, gx = gx0 + cc;
    uint4 v = make_uint4(0u, 0u, 0u, 0u);
    if (gy >= 0 && gy < HP && gx >= 0 && gx < HP) v = xb[gy*HP + gx];
    float4 f0, f1;
    f0.x = __uint_as_float(v.x << 16);
    f0.y = __uint_as_float(v.x & 0xffff0000u);
    f0.z = __uint_as_float(v.y << 16);
    f0.w = __uint_as_float(v.y & 0xffff0000u);
    f1.x = __uint_as_float(v.z << 16);
    f1.y = __uint_as_float(v.z & 0xffff0000u);
    f1.z = __uint_as_float(v.w << 16);
    f1.w = __uint_as_float(v.w & 0xffff0000u);
    xtA[r][cc] = f0;
    xtB[r][cc] = f1;
  }
  __syncthreads();
  int il = tid >> 5, jl = tid & 31;
  int I = I0 + 1 + il, J = J0 + 1 + jl;
  int pix = I*HP + J;
  float acc[8];
#pragma unroll
  for (int c = 0; c < 8; ++c) acc[c] = 0.f;
  int ndd = (z == NZ-1) ? 1 : 2;
  unsigned short wv[2][NWIN];
  {
    int wrow0 = (dylo + WOFF2) * NWIN;
    const unsigned short* wp0 = wfb + ((size_t)k*NW + wrow0)*PSTR + pix;
#pragma unroll
    for (int dxw = 0; dxw < NWIN; ++dxw) wv[0][dxw] = wp0[(size_t)dxw*PSTR];
    if (ndd == 2) {
      const unsigned short* wp1 = wp0 + (size_t)NWIN*PSTR;
#pragma unroll
      for (int dxw = 0; dxw < NWIN; ++dxw) wv[1][dxw] = wp1[(size_t)dxw*PSTR];
    }
  }
#pragma unroll
  for (int dd = 0; dd < 2; ++dd) {
    if (dd < ndd) {
      int r = il + dd;
#pragma unroll
      for (int dxw = 0; dxw < NWIN; ++dxw) {
        float wgt = __uint_as_float((unsigned)wv[dd][dxw] << 16);
        float4 x0 = xtA[r][jl + dxw];
        float4 x1 = xtB[r][jl + dxw];
        acc[0] += wgt * x0.x; acc[1] += wgt * x0.y;
        acc[2] += wgt * x0.z; acc[3] += wgt * x0.w;
        acc[4] += wgt * x1.x; acc[5] += wgt * x1.y;
        acc[6] += wgt * x1.z; acc[7] += wgt * x1.w;
      }
    }
  }
  int px64 = (I-1)*64 + (J-1);
#pragma unroll
  for (int c = 0; c < 8; ++c)
    accb2[((z*56 + k*8 + c)*4096) + px64] = acc[c];
}

__global__ __launch_bounds__(256) void k_final(const float* __restrict__ y,
    const float* __restrict__ accb2, float* __restrict__ out) {
  int idx = blockIdx.x * 256 + threadIdx.x;
  int ch = idx >> 12, px = idx & 4095;
  if (ch < 8) { out[idx] = y[ch*4096 + px]; return; }
  int kc = ch - 8, c = kc & 7;
  int i = px >> 6, j = px & 63;
  int I = i + 1, J = j + 1;
  int cy = min(I+5, HP-1) - max(I-4, 0) + 1;
  int cx = min(J+5, HP-1) - max(J-4, 0) + 1;
  float s = 0.f;
#pragma unroll
  for (int z = 0; z < NZ; ++z) s += accb2[(z*56 + kc)*4096 + px];
  out[idx] = s / (float)(cy*cx) - y[c*4096 + px];
}

extern "C" void kernel_launch(void* const* d_in, const int* in_sizes, int n_in,
                              void* d_out, int out_size, void* d_ws, size_t ws_size,
                              hipStream_t stream) {
  const float* x  = (const float*)d_in[0];
  const float* xe = (const float*)d_in[1];
  const float* ye = (const float*)d_in[2];
  const float* y  = (const float*)d_in[3];
  const float* lt = (const float*)d_in[4];
  float* ws   = (float*)d_ws;
  float* dist = ws + 30*QTOT;
  __hip_bfloat16* wf = (__hip_bfloat16*)(dist + (size_t)NW*QTOT);
  float* accb2 = dist;
  float* out = (float*)d_out;

  k_prep1<<<(QTOT + 255)/256, 256, 0, stream>>>(x, xe, ye, lt, ws);
  k_prep2<<<(QTOT + 255)/256, 256, 0, stream>>>(ws);
  k_dist<<<NW, 256, 0, stream>>>(ws, dist);
  k_weights<<<QBN, 256, 0, stream>>>(ws, dist, wf);
  k_boxw<<<KK*NW, 256, 0, stream>>>(wf);
  k_contract<<<dim3(16, NZ, KK), 256, 0, stream>>>(ws, (const unsigned short*)wf, accb2);
  k_final<<<out_size/256, 256, 0, stream>>>(y, accb2, out);
}

// Round 24
// 129.910 us; speedup vs baseline: 1.0238x; 1.0238x over previous
//
#include <hip/hip_runtime.h>
#include <hip/hip_bf16.h>

#define HP    66
#define QTOT  (HP*HP)          // 4356
#define NWIN  29
#define NW    (NWIN*NWIN)      // 841
#define KK    7
#define WOFF2 14
#define NZ    15               // dy-chunks for contraction (2 rows each)
#define QB    8                // queries per k_weights block
#define QBN   545              // ceil(QTOT/8)
#define NIT   27               // ceil(841/32)
#define NSEG6 396              // 66 lines x 6 segments of 11
#define PSTR  4368             // wf plane stride in u16 (546 uint4)

// ws float layout:
// 0        : yex    [QTOT][8] interleaved f32
// 8*QTOT   : xex    [QTOT][8] interleaved f32
// 16*QTOT  : x66b   [QTOT] uint4 (8 bf16 channels packed)
// 24*QTOT  : sqye/sqxe/lt66/n2q/n2db/ltb  (6 x QTOT)
// 30*QTOT  : dist   NW*QTOT f32 [w][q]   (reused as accb2 after k_weights)
// + NW*QTOT: wf bf16 [k][w][PSTR]

__global__ __launch_bounds__(256) void k_prep1(const float* __restrict__ x,
    const float* __restrict__ xe, const float* __restrict__ ye,
    const float* __restrict__ lt, float* __restrict__ ws) {
  int p = blockIdx.x * 256 + threadIdx.x;
  if (p >= QTOT) return;
  int i = p / HP, j = p % HP;
  bool in = (i >= 1 && i < HP-1 && j >= 1 && j < HP-1);
  int src = (i-1)*64 + (j-1);
  float vy[8], vx[8], vv[8];
  float sy = 0.f, sx = 0.f;
#pragma unroll
  for (int e = 0; e < 8; ++e) {
    vy[e] = in ? ye[e*4096 + src] : 0.f;
    vx[e] = in ? xe[e*4096 + src] : 0.f;
    vv[e] = in ? x [e*4096 + src] : 0.f;
    sy += vy[e]*vy[e]; sx += vx[e]*vx[e];
  }
  float4* yp = (float4*)(ws + (size_t)p*8);
  float4* xp = (float4*)(ws + 8*QTOT + (size_t)p*8);
  yp[0] = make_float4(vy[0], vy[1], vy[2], vy[3]);
  yp[1] = make_float4(vy[4], vy[5], vy[6], vy[7]);
  xp[0] = make_float4(vx[0], vx[1], vx[2], vx[3]);
  xp[1] = make_float4(vx[4], vx[5], vx[6], vx[7]);
  unsigned wd[4];
#pragma unroll
  for (int e2 = 0; e2 < 4; ++e2) {
    unsigned lo = __bfloat16_as_ushort(__float2bfloat16(vv[2*e2]));
    unsigned hi = __bfloat16_as_ushort(__float2bfloat16(vv[2*e2+1]));
    wd[e2] = lo | (hi << 16);
  }
  uint4* xb = (uint4*)(ws + 16*QTOT);
  uint4 v4; v4.x = wd[0]; v4.y = wd[1]; v4.z = wd[2]; v4.w = wd[3];
  xb[p] = v4;
  ws[24*QTOT + p] = sy;
  ws[25*QTOT + p] = sx;
  ws[26*QTOT + p] = in ? lt[src] : 0.f;
}

__global__ __launch_bounds__(256) void k_prep2(float* __restrict__ ws) {
  int p = blockIdx.x * 256 + threadIdx.x;
  if (p >= QTOT) return;
  int i = p / HP, j = p % HP;
  const float* sqye = ws + 24*QTOT;
  const float* sqxe = ws + 25*QTOT;
  const float* lt66 = ws + 26*QTOT;
  float a = 0.f, b = 0.f, c = 0.f;
  for (int u = -5; u <= 4; ++u) {
    int ii = i + u; if (ii < 0 || ii >= HP) continue;
    for (int v = -5; v <= 4; ++v) {
      int jj = j + v; if (jj < 0 || jj >= HP) continue;
      int o = ii*HP + jj;
      a += sqye[o]; b += sqxe[o]; c += lt66[o];
    }
  }
  ws[27*QTOT + p] = a;
  ws[28*QTOT + p] = b;
  ws[29*QTOT + p] = c * 0.01f;
}

// one block per shift w: dist plane [w][q]; flat LDS; register-rotation box
// [-5,+4] with 6-way segmented lines (chains of 11); coalesced f4 store
__global__ __launch_bounds__(256) void k_dist(const float* __restrict__ ws,
                                              float* __restrict__ dist) {
  __shared__ float4 s4[QTOT/4];         // flat f32[QTOT], 16B aligned
  __shared__ float h[QTOT];
  float* s = (float*)s4;
  int w = blockIdx.x, tid = threadIdx.x;
  int dy = w / NWIN - WOFF2, dx = w % NWIN - WOFF2;
  const float* yex = ws;
  const float* xex = ws + 8*QTOT;
  const float* n2q  = ws + 27*QTOT;
  const float* n2db = ws + 28*QTOT;
  for (int p = tid; p < QTOT; p += 256) {
    int i = p / HP, j = p % HP;
    int ii = i + dy, jj = j + dx;
    float sv = 0.f;
    if (ii >= 0 && ii < HP && jj >= 0 && jj < HP) {
      int p2 = ii*HP + jj;
      const float4* yp = (const float4*)(yex + (size_t)p*8);
      const float4* xp = (const float4*)(xex + (size_t)p2*8);
      float4 a0 = yp[0], a1 = yp[1], b0 = xp[0], b1 = xp[1];
      sv += a0.x*b0.x; sv += a0.y*b0.y; sv += a0.z*b0.z; sv += a0.w*b0.w;
      sv += a1.x*b1.x; sv += a1.y*b1.y; sv += a1.z*b1.z; sv += a1.w*b1.w;
    }
    s[p] = sv;
  }
  __syncthreads();
  for (int task = tid; task < NSEG6; task += 256) {  // h-pass [-5,+4]
    int row = task % HP, seg = task / HP, c0 = seg*11;
    const float* ar = s + row*HP;
    float* hr = h + row*HP;
    float w9[9]; float sum = 0.f;
#pragma unroll
    for (int t = 0; t < 9; ++t) {
      int jj = c0 - 5 + t;
      float v = (jj >= 0) ? ar[jj] : 0.f;
      w9[t] = v; sum += v;
    }
#pragma unroll
    for (int t = 0; t < 11; ++t) {
      int j = c0 + t, jn = j + 4;
      float nv = (jn < HP) ? ar[jn] : 0.f;
      sum += nv;
      hr[j] = sum;
      sum -= w9[t % 9];
      w9[t % 9] = nv;
    }
  }
  __syncthreads();
  for (int task = tid; task < NSEG6; task += 256) {  // v-pass + epilogue -> s
    int col = task % HP, seg = task / HP, r0 = seg*11;
    float w9[9]; float sum = 0.f;
#pragma unroll
    for (int t = 0; t < 9; ++t) {
      int ii = r0 - 5 + t;
      float v = (ii >= 0) ? h[ii*HP + col] : 0.f;
      w9[t] = v; sum += v;
    }
#pragma unroll
    for (int t = 0; t < 11; ++t) {
      int i = r0 + t, in2 = i + 4;
      float nv = (in2 < HP) ? h[in2*HP + col] : 0.f;
      sum += nv;
      float cr = sum;
      int p = i*HP + col;
      int ii = i + dy, jj = col + dx;
      bool valid = (ii >= 0 && ii < HP && jj >= 0 && jj < HP);
      float dv = 1e10f;
      if (valid && !(dy == 0 && dx == 0))
        dv = n2q[p] + n2db[ii*HP + jj] - 2.f * cr;
      s[p] = dv;                        // s dead after h-pass; no race
      sum -= w9[t % 9];
      w9[t % 9] = nv;
    }
  }
  __syncthreads();
  float4* dq = (float4*)(dist + (size_t)w*QTOT);
  for (int p4 = tid; p4 < QTOT/4; p4 += 256)   // coalesced store
    dq[p4] = s4[p4];
}

// 8 queries/block (qb XCD-swizzled); lv[] only; writes into wf[k][w][PSTR]
__global__ __launch_bounds__(256) void k_weights(const float* __restrict__ ws,
    const float* __restrict__ dist, __hip_bfloat16* __restrict__ wf) {
  __shared__ float mh[32], sh[32];
  int tid = threadIdx.x;
  int bid = blockIdx.x;                 // 545 blocks; m204 bijection (68,r=1)
  int xcd = bid & 7, idx = bid >> 3;
  int qb = (xcd == 0) ? idx : (69 + (xcd-1)*68 + idx);
  int qq = tid & (QB-1);
  int q = qb * QB + qq;
  bool qok = q < QTOT;
  int qs = qok ? q : (QTOT - 1);
  int wg = tid >> 3;             // 0..31
  int wave = tid >> 6;           // 0..3
  float invT = __expf(-ws[29*QTOT + qs]);
  float lv[NIT];
#pragma unroll
  for (int it = 0; it < NIT; ++it) {
    int w = wg + it*32;
    lv[it] = (qok && w < NW) ? (-dist[w*QTOT + qs] * invT) : -3.0e38f;
  }
  for (int k = 0; k < KK; ++k) {
    float pm = -3.0e38f;
#pragma unroll
    for (int it = 0; it < NIT; ++it) pm = fmaxf(pm, lv[it]);
    pm = fmaxf(pm, __shfl_xor(pm, 8, 64));
    pm = fmaxf(pm, __shfl_xor(pm, 16, 64));
    pm = fmaxf(pm, __shfl_xor(pm, 32, 64));
    if ((tid & 63) < QB) mh[wave*QB + qq] = pm;
    __syncthreads();
    float m = fmaxf(fmaxf(mh[qq], mh[QB+qq]), fmaxf(mh[2*QB+qq], mh[3*QB+qq]));
    float psum = 0.f;
#pragma unroll
    for (int it = 0; it < NIT; ++it) psum += __expf(lv[it] - m);
    psum += __shfl_xor(psum, 8, 64);
    psum += __shfl_xor(psum, 16, 64);
    psum += __shfl_xor(psum, 32, 64);
    if ((tid & 63) < QB) sh[wave*QB + qq] = psum;
    __syncthreads();
    float invden = 1.0f / (sh[qq] + sh[QB+qq] + sh[2*QB+qq] + sh[3*QB+qq]);
    size_t kbase = (size_t)k*NW*PSTR + q;
#pragma unroll
    for (int it = 0; it < NIT; ++it) {
      int w = wg + it*32;
      if (qok && w < NW) {
        float wgt = __expf(lv[it] - m) * invden;
        wf[kbase + (size_t)w*PSTR] = __float2bfloat16(wgt);
        if (k < KK-1 && wgt > 1e-9f)
          lv[it] += __logf(fmaxf(1.f - wgt, 1e-6f));
      }
    }
    __syncthreads();
  }
}

// one 256t block per (k,w) plane: FULLY COALESCED in-place plane load/store
// (546 contiguous uint4); box in flat bf16 LDS (17.5KB -> 8 blocks/CU);
// both passes 6-way segmented (chains of 11); race-free: a->h, h->a.
__global__ __launch_bounds__(256) void k_boxw(__hip_bfloat16* __restrict__ wfp) {
  __shared__ uint4 au4[546];            // flat bf16[4368]
  __shared__ uint4 hu4[546];            // flat bf16[4368] intermediate
  int bid = blockIdx.x;                 // 0..KK*NW-1
  uint4* plane = (uint4*)(wfp + (size_t)bid*PSTR);
  int tid = threadIdx.x;
  for (int qb = tid; qb < 546; qb += 256)
    au4[qb] = plane[qb];
  __syncthreads();
  const unsigned short* a16 = (const unsigned short*)au4;
  unsigned short* h16 = (unsigned short*)hu4;
  for (int task = tid; task < NSEG6; task += 256) {  // h-pass [-4,+5]
    int row = task % HP, seg = task / HP, c0 = seg*11;
    const unsigned short* ar = a16 + row*HP;
    unsigned short* hr = h16 + row*HP;
    float w9[9]; float sum = 0.f;
#pragma unroll
    for (int t = 0; t < 9; ++t) {
      int jj = c0 - 4 + t;
      float v = (jj >= 0) ? __uint_as_float((unsigned)ar[jj] << 16) : 0.f;
      w9[t] = v; sum += v;
    }
#pragma unroll
    for (int t = 0; t < 11; ++t) {
      int j = c0 + t, jn = j + 5;
      float nv = (jn < HP) ? __uint_as_float((unsigned)ar[jn] << 16) : 0.f;
      sum += nv;
      hr[j] = __bfloat16_as_ushort(__float2bfloat16(sum));
      sum -= w9[t % 9];
      w9[t % 9] = nv;
    }
  }
  __syncthreads();
  unsigned short* a16w = (unsigned short*)au4;
  for (int task = tid; task < NSEG6; task += 256) {  // v-pass [-4,+5]
    int col = task % HP, seg = task / HP, r0 = seg*11;
    float w9[9]; float sum = 0.f;
#pragma unroll
    for (int t = 0; t < 9; ++t) {
      int ii = r0 - 4 + t;
      float v = (ii >= 0) ? __uint_as_float((unsigned)h16[ii*HP + col] << 16) : 0.f;
      w9[t] = v; sum += v;
    }
#pragma unroll
    for (int t = 0; t < 11; ++t) {
      int i = r0 + t, in2 = i + 5;
      float nv = (in2 < HP) ? __uint_as_float((unsigned)h16[in2*HP + col] << 16) : 0.f;
      sum += nv;
      a16w[i*HP + col] = __bfloat16_as_ushort(__float2bfloat16(sum));
      sum -= w9[t % 9];
      w9[t % 9] = nv;
    }
  }
  __syncthreads();
  for (int qb = tid; qb < 546; qb += 256)     // coalesced in-place store
    plane[qb] = au4[qb];
}

// grid (16 tiles of 8x32, NZ=15, KK) = 1680 blocks. Full-line wf reads
// (32 contiguous u16 per w-row = one 64B line, 52MB fetch) + f32 inner
// loop: bf16 x staged ONCE and unpacked into two float4 LDS arrays.
__global__ __launch_bounds__(256) void k_contract(const float* __restrict__ ws,
    const unsigned short* __restrict__ wfb, float* __restrict__ accb2) {
  __shared__ float4 xtA[9][60];
  __shared__ float4 xtB[9][60];
  int t = blockIdx.x, z = blockIdx.y, k = blockIdx.z, tid = threadIdx.x;
  int I0 = (t >> 1) * 8, J0 = (t & 1) * 32;
  int dylo = -WOFF2 + 2*z;
  int gy0 = I0 + 1 + dylo, gx0 = J0 - 13;
  const uint4* xb = (const uint4*)(ws + 16*QTOT);
  for (int idx = tid; idx < 9*60; idx += 256) {
    int r = idx / 60, cc = idx % 60;
    int gy = gy0 + r, gx = gx0 + cc;
    uint4 v = make_uint4(0u, 0u, 0u, 0u);
    if (gy >= 0 && gy < HP && gx >= 0 && gx < HP) v = xb[gy*HP + gx];
    float4 f0, f1;
    f0.x = __uint_as_float(v.x << 16);
    f0.y = __uint_as_float(v.x & 0xffff0000u);
    f0.z = __uint_as_float(v.y << 16);
    f0.w = __uint_as_float(v.y & 0xffff0000u);
    f1.x = __uint_as_float(v.z << 16);
    f1.y = __uint_as_float(v.z & 0xffff0000u);
    f1.z = __uint_as_float(v.w << 16);
    f1.w = __uint_as_float(v.w & 0xffff0000u);
    xtA[r][cc] = f0;
    xtB[r][cc] = f1;
  }
  __syncthreads();
  int il = tid >> 5, jl = tid & 31;
  int I = I0 + 1 + il, J = J0 + 1 + jl;
  int pix = I*HP + J;
  float acc[8];
#pragma unroll
  for (int c = 0; c < 8; ++c) acc[c] = 0.f;
  int ndd = (z == NZ-1) ? 1 : 2;
  for (int dd = 0; dd < ndd; ++dd) {
    int wrow = (dylo + dd + WOFF2) * NWIN;
    const unsigned short* wp = wfb + ((size_t)k*NW + wrow)*PSTR + pix;
    unsigned short wv[NWIN];
#pragma unroll
    for (int dxw = 0; dxw < NWIN; ++dxw) wv[dxw] = wp[(size_t)dxw*PSTR];
    int r = il + dd;
#pragma unroll
    for (int dxw = 0; dxw < NWIN; ++dxw) {
      float wgt = __uint_as_float((unsigned)wv[dxw] << 16);
      float4 x0 = xtA[r][jl + dxw];
      float4 x1 = xtB[r][jl + dxw];
      acc[0] += wgt * x0.x; acc[1] += wgt * x0.y;
      acc[2] += wgt * x0.z; acc[3] += wgt * x0.w;
      acc[4] += wgt * x1.x; acc[5] += wgt * x1.y;
      acc[6] += wgt * x1.z; acc[7] += wgt * x1.w;
    }
  }
  int px64 = (I-1)*64 + (J-1);
#pragma unroll
  for (int c = 0; c < 8; ++c)
    accb2[((z*56 + k*8 + c)*4096) + px64] = acc[c];
}

__global__ __launch_bounds__(256) void k_final(const float* __restrict__ y,
    const float* __restrict__ accb2, float* __restrict__ out) {
  int idx = blockIdx.x * 256 + threadIdx.x;
  int ch = idx >> 12, px = idx & 4095;
  if (ch < 8) { out[idx] = y[ch*4096 + px]; return; }
  int kc = ch - 8, c = kc & 7;
  int i = px >> 6, j = px & 63;
  int I = i + 1, J = j + 1;
  int cy = min(I+5, HP-1) - max(I-4, 0) + 1;
  int cx = min(J+5, HP-1) - max(J-4, 0) + 1;
  float s = 0.f;
#pragma unroll
  for (int z = 0; z < NZ; ++z) s += accb2[(z*56 + kc)*4096 + px];
  out[idx] = s / (float)(cy*cx) - y[c*4096 + px];
}

extern "C" void kernel_launch(void* const* d_in, const int* in_sizes, int n_in,
                              void* d_out, int out_size, void* d_ws, size_t ws_size,
                              hipStream_t stream) {
  const float* x  = (const float*)d_in[0];
  const float* xe = (const float*)d_in[1];
  const float* ye = (const float*)d_in[2];
  const float* y  = (const float*)d_in[3];
  const float* lt = (const float*)d_in[4];
  float* ws   = (float*)d_ws;
  float* dist = ws + 30*QTOT;
  __hip_bfloat16* wf = (__hip_bfloat16*)(dist + (size_t)NW*QTOT);
  float* accb2 = dist;
  float* out = (float*)d_out;

  k_prep1<<<(QTOT + 255)/256, 256, 0, stream>>>(x, xe, ye, lt, ws);
  k_prep2<<<(QTOT + 255)/256, 256, 0, stream>>>(ws);
  k_dist<<<NW, 256, 0, stream>>>(ws, dist);
  k_weights<<<QBN, 256, 0, stream>>>(ws, dist, wf);
  k_boxw<<<KK*NW, 256, 0, stream>>>(wf);
  k_contract<<<dim3(16, NZ, KK), 256, 0, stream>>>(ws, (const unsigned short*)wf, accb2);
  k_final<<<out_size/256, 256, 0, stream>>>(y, accb2, out);
}